// Round 1
// baseline (350.903 us; speedup 1.0000x reference)
//
#include <hip/hip_runtime.h>

typedef short bf16x8 __attribute__((ext_vector_type(8)));
typedef float f32x4 __attribute__((ext_vector_type(4)));

__device__ __forceinline__ unsigned short f2bf(float f) {
  union { float f; unsigned u; } v; v.f = f;
  unsigned r = v.u + 0x7fffu + ((v.u >> 16) & 1u);
  return (unsigned short)(r >> 16);
}

// ---------------------------------------------------------------------------
// prep: u[b,q,h] = Wg1[:, 0:26] @ x_flat[b,q]
//       v[b,p,h] = Wg1[:, 26:52] @ x_flat[b,p] + Wg1[:, 52:180] @ qst[b] + bg1
// grid (64, 8): b x q-chunk; 256 threads = one h each.
// Also zeroes xg (the x_g accumulator) once per batch.
// ---------------------------------------------------------------------------
__global__ __launch_bounds__(256) void prep_kernel(
    const float* __restrict__ x, const float* __restrict__ qst,
    const float* __restrict__ Wg1, const float* __restrict__ bg1,
    float* __restrict__ u, float* __restrict__ v, float* __restrict__ xg)
{
  const int b = blockIdx.x;
  const int qc = blockIdx.y;
  const int h = threadIdx.x;
  if (qc == 0) xg[(b << 8) + h] = 0.f;

  __shared__ float qs_s[128];
  __shared__ float xf_s[26];
  if (h < 128) qs_s[h] = qst[(b << 7) + h];
  __syncthreads();

  const float2* wrow2 = (const float2*)(Wg1 + h * 180);  // 180 floats, 2-aligned
  float qv = bg1[h];
  #pragma unroll 8
  for (int j = 0; j < 64; ++j) {           // cols 52..179 (qst part)
    float2 w = wrow2[26 + j];
    qv += w.x * qs_s[2 * j] + w.y * qs_s[2 * j + 1];
  }

  for (int qi = 0; qi < 8; ++qi) {
    const int q = (qc << 3) + qi;
    __syncthreads();                        // protect xf_s before overwrite
    if (h < 24)       xf_s[h]  = x[((b * 24 + h) << 6) + q];
    else if (h == 24) xf_s[24] = (float)((q >> 3) - 4) * 0.25f;
    else if (h == 25) xf_s[25] = (float)((q & 7) - 4) * 0.25f;
    __syncthreads();
    float uv = 0.f, vv = qv;
    #pragma unroll
    for (int j = 0; j < 13; ++j) {
      float2 wa = wrow2[j];                 // cols 0..25   (x_i part)
      float2 wb = wrow2[13 + j];            // cols 26..51  (x_j part)
      uv += wa.x * xf_s[2 * j] + wa.y * xf_s[2 * j + 1];
      vv += wb.x * xf_s[2 * j] + wb.y * xf_s[2 * j + 1];
    }
    u[(((b << 6) + q) << 8) + h] = uv;
    v[(((b << 6) + q) << 8) + h] = vv;
  }
}

// ---------------------------------------------------------------------------
// fp32 -> bf16 weight conversion (Wg2/Wg3/Wg4), 65536 elements per call
// ---------------------------------------------------------------------------
__global__ void wconv_kernel(const float* __restrict__ W,
                             unsigned short* __restrict__ out) {
  int i = blockIdx.x * blockDim.x + threadIdx.x;
  out[i] = f2bf(W[i]);
}

// ---------------------------------------------------------------------------
// g-MLP layers 2..4 fused. One WG = 128 pair rows (1 batch, 2 p x 64 q).
// X tile [128][264] bf16 in LDS (+8 pad: row stride 132 dwords = bank+4/lane,
// 2-way conflict = free). 8 waves as 2(M) x 4(N); each wave: 64x64 output,
// acc = 4x4 fragments of mfma_f32_16x16x32_bf16.
// B-fragments load straight from L2-resident bf16 weights (no LDS staging).
// After g4: relu+bias, reduce rows in-wave (shfl_xor 16/32), atomicAdd to xg.
// ---------------------------------------------------------------------------
__global__ __launch_bounds__(512) void g_mlp_kernel(
    const float* __restrict__ u, const float* __restrict__ v,
    const unsigned short* __restrict__ Wb,   // [3][256][256] bf16
    const float* __restrict__ bg2, const float* __restrict__ bg3,
    const float* __restrict__ bg4,
    float* __restrict__ xg)
{
  __shared__ unsigned short Xs[128][264];

  const int t = threadIdx.x;
  const int wg = blockIdx.x;
  const int b = wg >> 5;                 // 32 WGs per batch
  const int p0 = (wg & 31) << 1;         // 2 p-values per WG
  const int lane = t & 63;
  const int wid = t >> 6;
  const int wr = wid >> 2, wc = wid & 3;
  const int l15 = lane & 15, l16 = lane >> 4;

  // ---- phase 0: X = relu(u[q] + v[p]) as bf16 ----
  {
    const int h0 = (t & 31) << 3;        // 8 consecutive h per thread
    const int mb_ = t >> 5;              // 16 rows per pass
    #pragma unroll
    for (int it = 0; it < 8; ++it) {
      const int m = (it << 4) + mb_;
      const int q = m & 63, p = p0 + (m >> 6);
      const float4* up = (const float4*)(u + ((((b << 6) + q) << 8) + h0));
      const float4* vp = (const float4*)(v + ((((b << 6) + p) << 8) + h0));
      float4 u0 = up[0], u1 = up[1];
      float4 v0 = vp[0], v1 = vp[1];
      union { unsigned short o[8]; uint4 vec; } pk;
      pk.o[0] = f2bf(fmaxf(u0.x + v0.x, 0.f));
      pk.o[1] = f2bf(fmaxf(u0.y + v0.y, 0.f));
      pk.o[2] = f2bf(fmaxf(u0.z + v0.z, 0.f));
      pk.o[3] = f2bf(fmaxf(u0.w + v0.w, 0.f));
      pk.o[4] = f2bf(fmaxf(u1.x + v1.x, 0.f));
      pk.o[5] = f2bf(fmaxf(u1.y + v1.y, 0.f));
      pk.o[6] = f2bf(fmaxf(u1.z + v1.z, 0.f));
      pk.o[7] = f2bf(fmaxf(u1.w + v1.w, 0.f));
      *(uint4*)&Xs[m][h0] = pk.vec;
    }
  }
  __syncthreads();

  const int arow = (wr << 6) + l15;      // A-fragment row for this lane
  const int kb0 = l16 << 3;              // A/B fragment k sub-offset

  for (int layer = 0; layer < 3; ++layer) {
    const unsigned short* W = Wb + (layer << 16);
    const float* bgl = (layer == 0) ? bg2 : (layer == 1) ? bg3 : bg4;

    f32x4 acc[4][4];
    #pragma unroll
    for (int mi = 0; mi < 4; ++mi)
      #pragma unroll
      for (int ni = 0; ni < 4; ++ni)
        acc[mi][ni] = (f32x4){0.f, 0.f, 0.f, 0.f};

    #pragma unroll 2
    for (int kc = 0; kc < 8; ++kc) {
      const int k = (kc << 5) + kb0;
      bf16x8 a[4], bb[4];
      #pragma unroll
      for (int mi = 0; mi < 4; ++mi)
        a[mi] = *(const bf16x8*)&Xs[arow + (mi << 4)][k];
      #pragma unroll
      for (int ni = 0; ni < 4; ++ni) {
        const int n = (wc << 6) + (ni << 4) + l15;
        bb[ni] = *(const bf16x8*)&W[(n << 8) + k];    // W[n][k..k+7]
      }
      #pragma unroll
      for (int mi = 0; mi < 4; ++mi)
        #pragma unroll
        for (int ni = 0; ni < 4; ++ni)
          acc[mi][ni] = __builtin_amdgcn_mfma_f32_16x16x32_bf16(
              a[mi], bb[ni], acc[mi][ni], 0, 0, 0);
    }

    float bias[4];
    #pragma unroll
    for (int ni = 0; ni < 4; ++ni)
      bias[ni] = bgl[(wc << 6) + (ni << 4) + l15];

    __syncthreads();                      // everyone done READING Xs
    if (layer < 2) {
      // C/D layout (m89): col = lane&15, row = (lane>>4)*4 + reg
      #pragma unroll
      for (int mi = 0; mi < 4; ++mi) {
        const int gm = (wr << 6) + (mi << 4) + (l16 << 2);
        #pragma unroll
        for (int ni = 0; ni < 4; ++ni) {
          const int gn = (wc << 6) + (ni << 4) + l15;
          #pragma unroll
          for (int r = 0; r < 4; ++r)
            Xs[gm + r][gn] = f2bf(fmaxf(acc[mi][ni][r] + bias[ni], 0.f));
        }
      }
      __syncthreads();                    // Xs ready for next layer
    } else {
      // g4: relu + sum over this wave's 64 rows, then atomic into xg[b]
      #pragma unroll
      for (int ni = 0; ni < 4; ++ni) {
        float s = 0.f;
        #pragma unroll
        for (int mi = 0; mi < 4; ++mi)
          #pragma unroll
          for (int r = 0; r < 4; ++r)
            s += fmaxf(acc[mi][ni][r] + bias[ni], 0.f);
        s += __shfl_xor(s, 16);
        s += __shfl_xor(s, 32);
        if (l16 == 0)
          atomicAdd(&xg[(b << 8) + (wc << 6) + (ni << 4) + l15], s);
      }
    }
  }
}

// ---------------------------------------------------------------------------
// f-MLP + log_softmax, fp32. One block per batch.
// ---------------------------------------------------------------------------
__global__ __launch_bounds__(256) void f_mlp_kernel(
    const float* __restrict__ xg,
    const float* __restrict__ Wf1, const float* __restrict__ bf1,
    const float* __restrict__ Wf2, const float* __restrict__ bf2,
    const float* __restrict__ Wf3, const float* __restrict__ bf3,
    float* __restrict__ out)
{
  const int b = blockIdx.x, t = threadIdx.x;
  __shared__ float s0[256], s1[256];
  __shared__ float lg[28];
  s0[t] = xg[(b << 8) + t];
  __syncthreads();
  {
    const float4* w4 = (const float4*)(Wf1 + (t << 8));
    float acc = bf1[t];
    #pragma unroll 8
    for (int k = 0; k < 64; ++k) {
      float4 w = w4[k];
      acc += w.x * s0[4*k] + w.y * s0[4*k+1] + w.z * s0[4*k+2] + w.w * s0[4*k+3];
    }
    s1[t] = fmaxf(acc, 0.f);
  }
  __syncthreads();
  {
    const float4* w4 = (const float4*)(Wf2 + (t << 8));
    float acc = bf2[t];
    #pragma unroll 8
    for (int k = 0; k < 64; ++k) {
      float4 w = w4[k];
      acc += w.x * s1[4*k] + w.y * s1[4*k+1] + w.z * s1[4*k+2] + w.w * s1[4*k+3];
    }
    s0[t] = fmaxf(acc, 0.f);
  }
  __syncthreads();
  if (t < 28) {
    const float4* w4 = (const float4*)(Wf3 + (t << 8));
    float acc = bf3[t];
    for (int k = 0; k < 64; ++k) {
      float4 w = w4[k];
      acc += w.x * s0[4*k] + w.y * s0[4*k+1] + w.z * s0[4*k+2] + w.w * s0[4*k+3];
    }
    lg[t] = acc;
  }
  __syncthreads();
  if (t == 0) {
    float mx = lg[0];
    for (int i = 1; i < 28; ++i) mx = fmaxf(mx, lg[i]);
    float sum = 0.f;
    for (int i = 0; i < 28; ++i) sum += expf(lg[i] - mx);
    float lse = mx + logf(sum);
    for (int i = 0; i < 28; ++i) out[b * 28 + i] = lg[i] - lse;
  }
}

// ---------------------------------------------------------------------------
extern "C" void kernel_launch(void* const* d_in, const int* in_sizes, int n_in,
                              void* d_out, int out_size, void* d_ws, size_t ws_size,
                              hipStream_t stream) {
  (void)in_sizes; (void)n_in; (void)out_size; (void)ws_size;
  const float* x   = (const float*)d_in[0];
  const float* qst = (const float*)d_in[1];
  const float* Wg1 = (const float*)d_in[2];
  const float* bg1 = (const float*)d_in[3];
  const float* Wg2 = (const float*)d_in[4];
  const float* bg2 = (const float*)d_in[5];
  const float* Wg3 = (const float*)d_in[6];
  const float* bg3 = (const float*)d_in[7];
  const float* Wg4 = (const float*)d_in[8];
  const float* bg4 = (const float*)d_in[9];
  const float* Wf1 = (const float*)d_in[10];
  const float* bf1 = (const float*)d_in[11];
  const float* Wf2 = (const float*)d_in[12];
  const float* bf2 = (const float*)d_in[13];
  const float* Wf3 = (const float*)d_in[14];
  const float* bf3 = (const float*)d_in[15];
  float* out = (float*)d_out;

  char* ws = (char*)d_ws;
  float* u           = (float*)(ws);                                  // 4 MiB
  float* v           = (float*)(ws + (4u << 20));                     // 4 MiB
  float* xg          = (float*)(ws + (8u << 20));                     // 64 KiB
  unsigned short* Wb = (unsigned short*)(ws + (8u << 20) + (64u << 10)); // 384 KiB

  prep_kernel<<<dim3(64, 8), 256, 0, stream>>>(x, qst, Wg1, bg1, u, v, xg);
  wconv_kernel<<<256, 256, 0, stream>>>(Wg2, Wb);
  wconv_kernel<<<256, 256, 0, stream>>>(Wg3, Wb + 65536);
  wconv_kernel<<<256, 256, 0, stream>>>(Wg4, Wb + 131072);
  g_mlp_kernel<<<2048, 512, 0, stream>>>(u, v, Wb, bg2, bg3, bg4, xg);
  f_mlp_kernel<<<64, 256, 0, stream>>>(xg, Wf1, bf1, Wf2, bf2, Wf3, bf3, out);
}

// Round 3
// 279.655 us; speedup vs baseline: 1.2548x; 1.2548x over previous
//
#include <hip/hip_runtime.h>

typedef short bf16x8 __attribute__((ext_vector_type(8)));
typedef float f32x4 __attribute__((ext_vector_type(4)));

__device__ __forceinline__ unsigned short f2bf(float f) {
  union { float f; unsigned u; } v; v.f = f;
  unsigned r = v.u + 0x7fffu + ((v.u >> 16) & 1u);
  return (unsigned short)(r >> 16);
}

// X tile swizzle: short index for logical (row m, col h) in [128][256]
// -> 2-way max on all LDS paths (2-way is free per m136)
__device__ __forceinline__ int xidx(int m, int h) {
  return (m << 8) + (h ^ ((m & 7) << 3));
}
// W chunk swizzle: short index for (row n, k-in-chunk kk) in [256][32]
__device__ __forceinline__ int widx(int n, int kk) {
  return (n << 5) + (kk ^ (((n >> 1) & 3) << 3));
}

__device__ __forceinline__ void gload_lds16(void* lds, const void* g) {
  __builtin_amdgcn_global_load_lds(
      (const __attribute__((address_space(1))) unsigned int*)g,
      (__attribute__((address_space(3))) unsigned int*)lds, 16, 0, 0);
}

// ---------------------------------------------------------------------------
// prep: u[b,q,h] = Wg1[:, 0:26] @ x_flat[b,q]
//       v[b,p,h] = Wg1[:, 26:52] @ x_flat[b,p] + Wg1[:, 52:180] @ qst[b] + bg1
// Also zeroes xg.
// ---------------------------------------------------------------------------
__global__ __launch_bounds__(256) void prep_kernel(
    const float* __restrict__ x, const float* __restrict__ qst,
    const float* __restrict__ Wg1, const float* __restrict__ bg1,
    float* __restrict__ u, float* __restrict__ v, float* __restrict__ xg)
{
  const int b = blockIdx.x;
  const int qc = blockIdx.y;
  const int h = threadIdx.x;
  if (qc == 0) xg[(b << 8) + h] = 0.f;

  __shared__ float qs_s[128];
  __shared__ float xf_s[26];
  if (h < 128) qs_s[h] = qst[(b << 7) + h];
  __syncthreads();

  const float2* wrow2 = (const float2*)(Wg1 + h * 180);
  float qv = bg1[h];
  #pragma unroll 8
  for (int j = 0; j < 64; ++j) {
    float2 w = wrow2[26 + j];
    qv += w.x * qs_s[2 * j] + w.y * qs_s[2 * j + 1];
  }

  for (int qi = 0; qi < 8; ++qi) {
    const int q = (qc << 3) + qi;
    __syncthreads();
    if (h < 24)       xf_s[h]  = x[((b * 24 + h) << 6) + q];
    else if (h == 24) xf_s[24] = (float)((q >> 3) - 4) * 0.25f;
    else if (h == 25) xf_s[25] = (float)((q & 7) - 4) * 0.25f;
    __syncthreads();
    float uv = 0.f, vv = qv;
    #pragma unroll
    for (int j = 0; j < 13; ++j) {
      float2 wa = wrow2[j];
      float2 wb = wrow2[13 + j];
      uv += wa.x * xf_s[2 * j] + wa.y * xf_s[2 * j + 1];
      vv += wb.x * xf_s[2 * j] + wb.y * xf_s[2 * j + 1];
    }
    u[(((b << 6) + q) << 8) + h] = uv;
    v[(((b << 6) + q) << 8) + h] = vv;
  }
}

// ---------------------------------------------------------------------------
// wconv: fp32 W[256][256] (x3 layers) -> bf16 chunked+swizzled image:
//   Wc[layer][kc][ widx(n, kk) ],  chunk = 8192 shorts (16 KB) contiguous.
// A linear 16 KB copy of a chunk into LDS yields the swizzled B layout.
// ---------------------------------------------------------------------------
__global__ __launch_bounds__(256) void wconv_kernel(
    const float* __restrict__ Wg2, const float* __restrict__ Wg3,
    const float* __restrict__ Wg4, unsigned short* __restrict__ out)
{
  int i = blockIdx.x * 256 + threadIdx.x;     // 0..196607
  int layer = i >> 16, r = i & 65535;
  int n = r >> 8, k = r & 255;
  const float* W = (layer == 0) ? Wg2 : (layer == 1) ? Wg3 : Wg4;
  int kc = k >> 5, kk = k & 31;
  out[(layer << 16) + (kc << 13) + widx(n, kk)] = f2bf(W[r]);
}

// ---------------------------------------------------------------------------
// g-MLP layers 2..4 fused, 2-phase pipelined.
// Block = 512 thr (8 waves, 2M x 4N), M-tile 128 (1 batch, 2 p x 64 q).
// LDS: Xs 64 KB (XOR-swizzled) + W chunk double-buffer 2x16 KB = 96 KB.
// Per 32-K chunk: STAGE(next->alt) || ds_read A/B -> 16 MFMA (setprio) ->
// one __syncthreads (implicit vmcnt(0) drains the depth-1 prefetch).
// ---------------------------------------------------------------------------
__global__ __launch_bounds__(512) void g_mlp_kernel(
    const float* __restrict__ u, const float* __restrict__ v,
    const unsigned short* __restrict__ Wc,   // [3][8][8192] bf16 swizzled
    const float* __restrict__ bg2, const float* __restrict__ bg3,
    const float* __restrict__ bg4,
    float* __restrict__ xg)
{
  __shared__ unsigned short Xs[32768];       // [128][256] swizzled
  __shared__ unsigned short Wb[2][8192];     // chunk double buffer

  const int t = threadIdx.x;
  const int wg = blockIdx.x;
  const int b = wg >> 5;
  const int p0 = (wg & 31) << 1;
  const int lane = t & 63;
  const int wid = t >> 6;
  const int wr = wid >> 2, wc = wid & 3;
  const int l15 = lane & 15, l16 = lane >> 4;

  // ---- prologue: stage chunk 0 into Wb[0] (latency hides under phase 0) ----
  {
    const char* src = (const char*)Wc;
    gload_lds16(&Wb[0][t * 8],        src + t * 16);
    gload_lds16(&Wb[0][4096 + t * 8], src + 8192 + t * 16);
  }

  // ---- phase 0: Xs = relu(u[q] + v[p]) as bf16 (swizzled store) ----
  {
    const int h0 = (t & 31) << 3;
    const int mb_ = t >> 5;
    #pragma unroll
    for (int it = 0; it < 8; ++it) {
      const int m = (it << 4) + mb_;
      const int q = m & 63, p = p0 + (m >> 6);
      const float4* up = (const float4*)(u + ((((b << 6) + q) << 8) + h0));
      const float4* vp = (const float4*)(v + ((((b << 6) + p) << 8) + h0));
      float4 u0 = up[0], u1 = up[1];
      float4 v0 = vp[0], v1 = vp[1];
      union { unsigned short o[8]; uint4 vec; } pk;
      pk.o[0] = f2bf(fmaxf(u0.x + v0.x, 0.f));
      pk.o[1] = f2bf(fmaxf(u0.y + v0.y, 0.f));
      pk.o[2] = f2bf(fmaxf(u0.z + v0.z, 0.f));
      pk.o[3] = f2bf(fmaxf(u0.w + v0.w, 0.f));
      pk.o[4] = f2bf(fmaxf(u1.x + v1.x, 0.f));
      pk.o[5] = f2bf(fmaxf(u1.y + v1.y, 0.f));
      pk.o[6] = f2bf(fmaxf(u1.z + v1.z, 0.f));
      pk.o[7] = f2bf(fmaxf(u1.w + v1.w, 0.f));
      *(uint4*)&Xs[xidx(m, h0)] = pk.vec;
    }
  }
  __syncthreads();   // drains vmcnt(0): chunk 0 staged; Xs ready

  // per-lane constant address pieces
  const int arow = (wr << 6) + l15;               // + mi*16
  const int asw  = (l15 & 7) << 3;                // X swizzle term (rows step by 16)
  const int bko  = (l16 << 3) ^ (((l15 >> 1) & 3) << 3);  // W k-offset ^ swizzle

  int cur = 0;
  for (int layer = 0; layer < 3; ++layer) {
    const float* bgl = (layer == 0) ? bg2 : (layer == 1) ? bg3 : bg4;

    f32x4 acc[4][4];
    #pragma unroll
    for (int mi = 0; mi < 4; ++mi)
      #pragma unroll
      for (int ni = 0; ni < 4; ++ni)
        acc[mi][ni] = (f32x4){0.f, 0.f, 0.f, 0.f};

    for (int kc = 0; kc < 8; ++kc) {
      const int tt = (layer << 3) + kc;
      // ---- STAGE next chunk into alternate buffer ----
      if (tt < 23) {
        const char* src = (const char*)Wc + ((tt + 1) << 14);
        unsigned short* dst = Wb[cur ^ 1];
        gload_lds16(&dst[t * 8],        src + t * 16);
        gload_lds16(&dst[4096 + t * 8], src + 8192 + t * 16);
      }
      // ---- fragments from LDS ----
      const int kpart = (kc << 5) + (l16 << 3);
      bf16x8 a[4], bb[4];
      #pragma unroll
      for (int mi = 0; mi < 4; ++mi)
        a[mi] = *(const bf16x8*)&Xs[((arow + (mi << 4)) << 8) + (kpart ^ asw)];
      #pragma unroll
      for (int ni = 0; ni < 4; ++ni) {
        const int n = (wc << 6) + (ni << 4) + l15;
        bb[ni] = *(const bf16x8*)&Wb[cur][(n << 5) + bko];
      }
      __builtin_amdgcn_s_setprio(1);
      #pragma unroll
      for (int mi = 0; mi < 4; ++mi)
        #pragma unroll
        for (int ni = 0; ni < 4; ++ni)
          acc[mi][ni] = __builtin_amdgcn_mfma_f32_16x16x32_bf16(
              a[mi], bb[ni], acc[mi][ni], 0, 0, 0);
      __builtin_amdgcn_s_setprio(0);
      __syncthreads();   // implicit vmcnt(0)+lgkmcnt(0): next chunk staged
      cur ^= 1;
    }

    float bias[4];
    #pragma unroll
    for (int ni = 0; ni < 4; ++ni)
      bias[ni] = bgl[(wc << 6) + (ni << 4) + l15];

    if (layer < 2) {
      // write-back relu(acc+bias) into swizzled Xs; C/D: col=l15, row=l16*4+r
      #pragma unroll
      for (int mi = 0; mi < 4; ++mi) {
        const int gm0 = (wr << 6) + (mi << 4) + (l16 << 2);
        #pragma unroll
        for (int ni = 0; ni < 4; ++ni) {
          const int gn = (wc << 6) + (ni << 4) + l15;
          #pragma unroll
          for (int r = 0; r < 4; ++r)
            Xs[xidx(gm0 + r, gn)] = f2bf(fmaxf(acc[mi][ni][r] + bias[ni], 0.f));
        }
      }
      __syncthreads();   // Xs ready for next layer
    } else {
      #pragma unroll
      for (int ni = 0; ni < 4; ++ni) {
        float s = 0.f;
        #pragma unroll
        for (int mi = 0; mi < 4; ++mi)
          #pragma unroll
          for (int r = 0; r < 4; ++r)
            s += fmaxf(acc[mi][ni][r] + bias[ni], 0.f);
        s += __shfl_xor(s, 16);
        s += __shfl_xor(s, 32);
        if (l16 == 0)
          atomicAdd(&xg[(b << 8) + (wc << 6) + (ni << 4) + l15], s);
      }
    }
  }
}

// ---------------------------------------------------------------------------
// f-MLP + log_softmax, fp32. One block per batch.
// ---------------------------------------------------------------------------
__global__ __launch_bounds__(256) void f_mlp_kernel(
    const float* __restrict__ xg,
    const float* __restrict__ Wf1, const float* __restrict__ bf1,
    const float* __restrict__ Wf2, const float* __restrict__ bf2,
    const float* __restrict__ Wf3, const float* __restrict__ bf3,
    float* __restrict__ out)
{
  const int b = blockIdx.x, t = threadIdx.x;
  __shared__ float s0[256], s1[256];
  __shared__ float lg[28];
  s0[t] = xg[(b << 8) + t];
  __syncthreads();
  {
    const float4* w4 = (const float4*)(Wf1 + (t << 8));
    float acc = bf1[t];
    #pragma unroll 8
    for (int k = 0; k < 64; ++k) {
      float4 w = w4[k];
      acc += w.x * s0[4*k] + w.y * s0[4*k+1] + w.z * s0[4*k+2] + w.w * s0[4*k+3];
    }
    s1[t] = fmaxf(acc, 0.f);
  }
  __syncthreads();
  {
    const float4* w4 = (const float4*)(Wf2 + (t << 8));
    float acc = bf2[t];
    #pragma unroll 8
    for (int k = 0; k < 64; ++k) {
      float4 w = w4[k];
      acc += w.x * s1[4*k] + w.y * s1[4*k+1] + w.z * s1[4*k+2] + w.w * s1[4*k+3];
    }
    s0[t] = fmaxf(acc, 0.f);
  }
  __syncthreads();
  if (t < 28) {
    const float4* w4 = (const float4*)(Wf3 + (t << 8));
    float acc = bf3[t];
    for (int k = 0; k < 64; ++k) {
      float4 w = w4[k];
      acc += w.x * s0[4*k] + w.y * s0[4*k+1] + w.z * s0[4*k+2] + w.w * s0[4*k+3];
    }
    lg[t] = acc;
  }
  __syncthreads();
  if (t == 0) {
    float mx = lg[0];
    for (int i = 1; i < 28; ++i) mx = fmaxf(mx, lg[i]);
    float sum = 0.f;
    for (int i = 0; i < 28; ++i) sum += expf(lg[i] - mx);
    float lse = mx + logf(sum);
    for (int i = 0; i < 28; ++i) out[b * 28 + i] = lg[i] - lse;
  }
}

// ---------------------------------------------------------------------------
extern "C" void kernel_launch(void* const* d_in, const int* in_sizes, int n_in,
                              void* d_out, int out_size, void* d_ws, size_t ws_size,
                              hipStream_t stream) {
  (void)in_sizes; (void)n_in; (void)out_size; (void)ws_size;
  const float* x   = (const float*)d_in[0];
  const float* qst = (const float*)d_in[1];
  const float* Wg1 = (const float*)d_in[2];
  const float* bg1 = (const float*)d_in[3];
  const float* Wg2 = (const float*)d_in[4];
  const float* bg2 = (const float*)d_in[5];
  const float* Wg3 = (const float*)d_in[6];
  const float* bg3 = (const float*)d_in[7];
  const float* Wg4 = (const float*)d_in[8];
  const float* bg4 = (const float*)d_in[9];
  const float* Wf1 = (const float*)d_in[10];
  const float* bf1 = (const float*)d_in[11];
  const float* Wf2 = (const float*)d_in[12];
  const float* bf2 = (const float*)d_in[13];
  const float* Wf3 = (const float*)d_in[14];
  const float* bf3 = (const float*)d_in[15];
  float* out = (float*)d_out;

  char* ws = (char*)d_ws;
  float* u           = (float*)(ws);                                     // 4 MiB
  float* v           = (float*)(ws + (4u << 20));                        // 4 MiB
  float* xg          = (float*)(ws + (8u << 20));                        // 64 KiB
  unsigned short* Wc = (unsigned short*)(ws + (8u << 20) + (64u << 10)); // 384 KiB

  prep_kernel<<<dim3(64, 8), 256, 0, stream>>>(x, qst, Wg1, bg1, u, v, xg);
  wconv_kernel<<<768, 256, 0, stream>>>(Wg2, Wg3, Wg4, Wc);
  g_mlp_kernel<<<2048, 512, 0, stream>>>(u, v, Wc, bg2, bg3, bg4, xg);
  f_mlp_kernel<<<64, 256, 0, stream>>>(xg, Wf1, bf1, Wf2, bf2, Wf3, bf3, out);
}